// Round 6
// baseline (222.349 us; speedup 1.0000x reference)
//
#include <hip/hip_runtime.h>

#define EPSV 0.001f

// ---------------------------------------------------------------------------
// Kernel A: MLP only. 2048 blocks x 256 threads; block = 8 rows of one MLP.
// All 2048 blocks are co-resident (17.7 KB LDS -> 8 blocks/CU), W1 stays
// L2-resident (512 KB total), so this runs in ~one block duration.
//   wd[bz*1024+n] = exp(mlp_d(x)[b,n,z]),  wu[...] = mlp_o(x)[b,n,z]
// ---------------------------------------------------------------------------
__global__ __launch_bounds__(256) void mlp_kernel(
    const float* __restrict__ x,
    const float* __restrict__ dW0, const float* __restrict__ db0,
    const float* __restrict__ dW1, const float* __restrict__ db1,
    const float* __restrict__ dW2, const float* __restrict__ db2,
    const float* __restrict__ oW0, const float* __restrict__ ob0,
    const float* __restrict__ oW1, const float* __restrict__ ob1,
    const float* __restrict__ oW2, const float* __restrict__ ob2,
    float* __restrict__ wd, float* __restrict__ wu)
{
    __shared__ float xs[8][32];
    __shared__ float h1[8][260];   // pad 260: layer-2 reads hit banks {0,8,16,24}+k
    __shared__ float h2[8][260];

    const int t     = threadIdx.x;
    const int mlpid = blockIdx.x;         // 0..2047
    const int msel  = mlpid & 1;          // 0 = diag MLP, 1 = offdiag MLP
    const int row0  = (mlpid >> 1) << 3;  // 8 rows of flattened (8192, 32) x

    const float* W0 = msel ? oW0 : dW0;  const float* b0 = msel ? ob0 : db0;
    const float* W1 = msel ? oW1 : dW1;  const float* b1 = msel ? ob1 : db1;
    const float* W2 = msel ? oW2 : dW2;  const float* b2 = msel ? ob2 : db2;

    // stage 8 input rows (256 floats, one per thread)
    ((float*)xs)[t] = x[row0 * 32 + t];
    __syncthreads();

    // ----- layer 1: (8 x 32) @ (32 x 256); thread t owns hidden unit t -----
    {
        float acc1[8];
        const float bb = b0[t];
        #pragma unroll
        for (int r = 0; r < 8; ++r) acc1[r] = bb;
        #pragma unroll
        for (int k4 = 0; k4 < 8; ++k4) {
            const float w0 = W0[(k4 * 4 + 0) * 256 + t];
            const float w1 = W0[(k4 * 4 + 1) * 256 + t];
            const float w2 = W0[(k4 * 4 + 2) * 256 + t];
            const float w3 = W0[(k4 * 4 + 3) * 256 + t];
            #pragma unroll
            for (int r = 0; r < 8; ++r) {
                const float4 h = *reinterpret_cast<const float4*>(&xs[r][k4 * 4]);
                acc1[r] = fmaf(h.w, w3, fmaf(h.z, w2, fmaf(h.y, w1, fmaf(h.x, w0, acc1[r]))));
            }
        }
        #pragma unroll
        for (int r = 0; r < 8; ++r) h1[r][t] = fmaxf(acc1[r], 0.0f);
    }
    __syncthreads();

    // ----- layer 2: (8 x 256) @ (256 x 256) -----
    // wave w owns output cols [64w, 64w+64); lane=(og 0..15, rg 0..3);
    // lane computes rows {2rg, 2rg+1} x cols {obase, +16, +32, +48}.
    // W1 read exactly once per wave (its own 64-col slice).
    {
        const int wv = t >> 6, l = t & 63;
        const int og = l & 15, rg = l >> 4;
        const int obase = wv * 64 + og;
        const int r0 = rg * 2;
        const float* Wp = W1 + obase;

        float acc2[2][4];
        {
            const float bj0 = b1[obase], bj1 = b1[obase + 16],
                        bj2 = b1[obase + 32], bj3 = b1[obase + 48];
            #pragma unroll
            for (int rr = 0; rr < 2; ++rr) {
                acc2[rr][0] = bj0; acc2[rr][1] = bj1;
                acc2[rr][2] = bj2; acc2[rr][3] = bj3;
            }
        }
        for (int k4 = 0; k4 < 64; ++k4) {
            float4 hv[2];
            #pragma unroll
            for (int rr = 0; rr < 2; ++rr)
                hv[rr] = *reinterpret_cast<const float4*>(&h1[r0 + rr][k4 * 4]);
            #pragma unroll
            for (int kk = 0; kk < 4; ++kk) {
                const float* wrow = Wp + (k4 * 4 + kk) * 256;
                const float wj0 = wrow[0],  wj1 = wrow[16],
                            wj2 = wrow[32], wj3 = wrow[48];
                #pragma unroll
                for (int rr = 0; rr < 2; ++rr) {
                    const float hvv = (kk == 0) ? hv[rr].x : (kk == 1) ? hv[rr].y
                                    : (kk == 2) ? hv[rr].z : hv[rr].w;
                    acc2[rr][0] = fmaf(hvv, wj0, acc2[rr][0]);
                    acc2[rr][1] = fmaf(hvv, wj1, acc2[rr][1]);
                    acc2[rr][2] = fmaf(hvv, wj2, acc2[rr][2]);
                    acc2[rr][3] = fmaf(hvv, wj3, acc2[rr][3]);
                }
            }
        }
        #pragma unroll
        for (int rr = 0; rr < 2; ++rr) {
            #pragma unroll
            for (int j = 0; j < 4; ++j)
                h2[r0 + rr][obase + 16 * j] = fmaxf(acc2[rr][j], 0.0f);
        }
    }
    __syncthreads();

    // ----- layer 3: (8 x 256) @ (256 x 8); threads 0..63 -> (row, z) -----
    if (t < 64) {
        const int r = t >> 3, z = t & 7;
        float a = b2[z];
        #pragma unroll 8
        for (int k4 = 0; k4 < 64; ++k4) {
            const float4 h = *reinterpret_cast<const float4*>(&h2[r][k4 * 4]);
            a = fmaf(h.x, W2[(k4 * 4 + 0) * 8 + z], a);
            a = fmaf(h.y, W2[(k4 * 4 + 1) * 8 + z], a);
            a = fmaf(h.z, W2[(k4 * 4 + 2) * 8 + z], a);
            a = fmaf(h.w, W2[(k4 * 4 + 3) * 8 + z], a);
        }
        const int n  = row0 + r;
        const int b  = n >> 10, nn = n & 1023;
        const int oi = ((b << 3) + z) * 1024 + nn;
        if (msel == 0) wd[oi] = expf(a);
        else           wu[oi] = a;
    }
}

// ---------------------------------------------------------------------------
// Kernel B: fill + band in one pass, PLAIN float4 stores (L2-aggregated,
// fillBuffer-class drain). One float4 per (thread, iter); grid-stride x8.
// Flat float4 index f: tsel = f>>24 (0=D,1=Bmat,2=P), bz = (f>>18)&63,
// i = (f>>8)&1023, c = f&255, cols [4c, 4c+3].
//   D:    [i][i]   = d[i]
//   Bmat: [i][i]   = d[i],           [i][i+1] = u[i]
//   P:    [i][i-1] = d[i-1]*u[i-1],  [i][i]   = d[i]^2+u[i-1]^2+eps,
//         [i][i+1] = d[i]*u[i]
// ---------------------------------------------------------------------------
__global__ __launch_bounds__(256) void fill_band_kernel(
    const float* __restrict__ wd, const float* __restrict__ wu,
    float4* __restrict__ out4)
{
    unsigned f = blockIdx.x * 256u + threadIdx.x;
    #pragma unroll
    for (int it = 0; it < 8; ++it) {
        const unsigned tsel = f >> 24;
        const unsigned rr   = f & 0xFFFFFFu;
        const unsigned bz   = rr >> 18;
        const int i  = (int)((rr >> 8) & 1023u);
        const int c  = (int)(f & 255u);
        const int j0 = c << 2;

        float4 v = make_float4(0.f, 0.f, 0.f, 0.f);
        if (j0 <= i + 1 && j0 + 3 >= i - 1) {      // window intersects band
            const float* dp = wd + (bz << 10);
            const float* up = wu + (bz << 10);
            const float di = dp[i];
            const float ui = up[i];
            const float dm = (i > 0) ? dp[i - 1] : 0.f;
            const float um = (i > 0) ? up[i - 1] : 0.f;
            float vv[4];
            #pragma unroll
            for (int q = 0; q < 4; ++q) {
                const int j = j0 + q;
                float val = 0.f;
                if (tsel == 0) {
                    if (j == i) val = di;
                } else if (tsel == 1) {
                    if (j == i)          val = di;
                    else if (j == i + 1) val = ui;
                } else {
                    if (j == i - 1)      val = dm * um;
                    else if (j == i)     val = fmaf(di, di, fmaf(um, um, EPSV));
                    else if (j == i + 1) val = di * ui;
                }
                vv[q] = val;
            }
            v = make_float4(vv[0], vv[1], vv[2], vv[3]);
        }
        out4[f] = v;
        f += 24576u * 256u;    // 24576 blocks * 256 thr * 8 it = 50331648 f4
    }
}

extern "C" void kernel_launch(void* const* d_in, const int* in_sizes, int n_in,
                              void* d_out, int out_size, void* d_ws, size_t ws_size,
                              hipStream_t stream) {
    const float* x   = (const float*)d_in[0];
    const float* dW0 = (const float*)d_in[1];
    const float* db0 = (const float*)d_in[2];
    const float* dW1 = (const float*)d_in[3];
    const float* db1 = (const float*)d_in[4];
    const float* dW2 = (const float*)d_in[5];
    const float* db2 = (const float*)d_in[6];
    const float* oW0 = (const float*)d_in[7];
    const float* ob0 = (const float*)d_in[8];
    const float* oW1 = (const float*)d_in[9];
    const float* ob1 = (const float*)d_in[10];
    const float* oW2 = (const float*)d_in[11];
    const float* ob2 = (const float*)d_in[12];

    float* wsf = (float*)d_ws;
    float* wd  = wsf;            // 64*1024 floats
    float* wu  = wsf + 65536;    // 64*1024 floats

    mlp_kernel<<<2048, 256, 0, stream>>>(x, dW0, db0, dW1, db1, dW2, db2,
                                         oW0, ob0, oW1, ob1, oW2, ob2, wd, wu);

    fill_band_kernel<<<24576, 256, 0, stream>>>(wd, wu, (float4*)d_out);
}